// Round 1
// baseline (262.883 us; speedup 1.0000x reference)
//
#include <hip/hip_runtime.h>

// ---------------------------------------------------------------------------
// HOI top-k selection, R=262144 rows x K=117 classes, topk=100, thresh=0.05
//
// Pipeline (4 kernels, all data-dependent control on device):
//  K1 k_hist    : full pass, LDS histogram of float-bit bins + opportunistic
//                 candidate collection for values >= ~0.898 (bin G_REL)
//  K2 k_thresh  : single block; find exact cutoff bin T (>=topk values above),
//                 decide whether K1's candidate buffer is a valid superset
//  K3 k_collect : fallback full pass (early-exits when K1 buffer is valid)
//  K4 k_final   : single block; filter cands to bins >= T, bitonic sort
//                 (value desc, index asc = stable top_k tie order), write out
// ---------------------------------------------------------------------------

#define NB        576          // histogram bins, top-16 float bits - BIN_BASE
#define BIN_BASE  15692        // (bits of 0.05f) >> 16
#define G_REL     538          // bin of 0.8984375f -> opportunistic collect
#define CAP       8192         // global candidate capacity
#define FCAP      2048         // K4 sort capacity (power of 2)
#define THRESH    0.05f
#define NEG_INF   __int_as_float(0xFF800000)

__device__ __forceinline__ int bin_of(float s) {
  // valid only for s > THRESH (positive floats: bit order == value order)
  int b = (int)(__float_as_uint(s) >> 16) - BIN_BASE;
  return b > (NB - 1) ? (NB - 1) : b;
}

template <int KC>
__global__ __launch_bounds__(512) void k_hist(
    const float4* __restrict__ hoi4, const float* __restrict__ ps,
    const float* __restrict__ os, int N4, int N, int Kc,
    int* __restrict__ g_hist, int* __restrict__ g_cnt,
    float* __restrict__ cand_v, int* __restrict__ cand_i) {
  __shared__ int lh[NB];
  for (int b = threadIdx.x; b < NB; b += blockDim.x) lh[b] = 0;
  __syncthreads();

  const int k = KC ? KC : Kc;
  const int stride = gridDim.x * blockDim.x;
  for (int t = blockIdx.x * blockDim.x + threadIdx.x; t < N4; t += stride) {
    float4 h = hoi4[t];
    int i0 = 4 * t;
    int q = i0 / k;            // constant K -> magic-mul
    int rem = i0 - q * k;
    float vals[4] = {h.x, h.y, h.z, h.w};
#pragma unroll
    for (int j = 0; j < 4; ++j) {
      if (rem == k) { rem = 0; ++q; }
      float bs = ps[q] * os[q];      // matches ref: box_scores = p*o
      float s = vals[j] * bs;        // scores = hoi * box_scores
      ++rem;
      if (s > THRESH) {
        int b = bin_of(s);
        atomicAdd(&lh[b], 1);
        if (b >= G_REL) {
          int slot = atomicAdd(g_cnt, 1);
          if (slot < CAP) { cand_v[slot] = s; cand_i[slot] = i0 + j; }
        }
      }
    }
  }
  // scalar tail (N % 4), handled by block 0 only
  if (blockIdx.x == 0) {
    const float* hoi = (const float*)hoi4;
    for (int i = N4 * 4 + threadIdx.x; i < N; i += blockDim.x) {
      int q = i / k;
      float s = hoi[i] * (ps[q] * os[q]);
      if (s > THRESH) {
        int b = bin_of(s);
        atomicAdd(&lh[b], 1);
        if (b >= G_REL) {
          int slot = atomicAdd(g_cnt, 1);
          if (slot < CAP) { cand_v[slot] = s; cand_i[slot] = i; }
        }
      }
    }
  }
  __syncthreads();
  for (int b = threadIdx.x; b < NB; b += blockDim.x) {
    int c = lh[b];
    if (c) atomicAdd(&g_hist[b], c);
  }
}

__global__ void k_thresh(const int* __restrict__ g_hist, int* __restrict__ g_cnt,
                         int* __restrict__ g_meta, int topk) {
  __shared__ int lh[NB];
  for (int b = threadIdx.x; b < NB; b += blockDim.x) lh[b] = g_hist[b];
  __syncthreads();
  if (threadIdx.x == 0) {
    int cum = 0, T = 0;
    for (int b = NB - 1; b >= 0; --b) {
      cum += lh[b];
      if (cum >= topk) { T = b; break; }
    }
    int cnt = g_cnt[0];
    // K1 buffer usable iff no overflow and all bins >= T were collected
    int mode = (cnt <= CAP && T >= G_REL) ? 0 : 1;
    if (mode) g_cnt[0] = 0;   // K3 recollects from scratch
    g_meta[0] = T;
    g_meta[1] = mode;
  }
}

template <int KC>
__global__ __launch_bounds__(512) void k_collect(
    const float4* __restrict__ hoi4, const float* __restrict__ ps,
    const float* __restrict__ os, int N4, int N, int Kc,
    const int* __restrict__ g_meta, int* __restrict__ g_cnt,
    float* __restrict__ cand_v, int* __restrict__ cand_i) {
  if (g_meta[1] == 0) return;   // K1's buffer is valid -> nothing to do
  const int T = g_meta[0];
  const int k = KC ? KC : Kc;
  const int stride = gridDim.x * blockDim.x;
  for (int t = blockIdx.x * blockDim.x + threadIdx.x; t < N4; t += stride) {
    float4 h = hoi4[t];
    int i0 = 4 * t;
    int q = i0 / k;
    int rem = i0 - q * k;
    float vals[4] = {h.x, h.y, h.z, h.w};
#pragma unroll
    for (int j = 0; j < 4; ++j) {
      if (rem == k) { rem = 0; ++q; }
      float s = vals[j] * (ps[q] * os[q]);
      ++rem;
      if (s > THRESH && bin_of(s) >= T) {
        int slot = atomicAdd(g_cnt, 1);
        if (slot < CAP) { cand_v[slot] = s; cand_i[slot] = i0 + j; }
      }
    }
  }
  if (blockIdx.x == 0) {
    const float* hoi = (const float*)hoi4;
    for (int i = N4 * 4 + threadIdx.x; i < N; i += blockDim.x) {
      int q = i / k;
      float s = hoi[i] * (ps[q] * os[q]);
      if (s > THRESH && bin_of(s) >= T) {
        int slot = atomicAdd(g_cnt, 1);
        if (slot < CAP) { cand_v[slot] = s; cand_i[slot] = i; }
      }
    }
  }
}

__global__ __launch_bounds__(1024) void k_final(
    const float* __restrict__ cand_v, const int* __restrict__ cand_i,
    const int* __restrict__ g_cnt, const int* __restrict__ g_meta,
    const float4* __restrict__ pbox, const float4* __restrict__ obox,
    const int* __restrict__ ocls, float* __restrict__ out, int topk, int Kc) {
  __shared__ float sv[FCAP];
  __shared__ int si[FCAP];
  __shared__ int scnt;
  if (threadIdx.x == 0) scnt = 0;
  __syncthreads();

  const int T = g_meta[0];
  int n = g_cnt[0];
  if (n > CAP) n = CAP;
  for (int t = threadIdx.x; t < n; t += blockDim.x) {
    float v = cand_v[t];
    if (bin_of(v) >= T) {
      int slot = atomicAdd(&scnt, 1);
      if (slot < FCAP) { sv[slot] = v; si[slot] = cand_i[t]; }
    }
  }
  __syncthreads();
  int m = scnt > FCAP ? FCAP : scnt;
  for (int t = threadIdx.x; t < FCAP; t += blockDim.x)
    if (t >= m) { sv[t] = NEG_INF; si[t] = 0x7FFFFFFF; }

  // bitonic sort: final order = value desc, index asc (stable-top_k ties)
  for (int kk = 2; kk <= FCAP; kk <<= 1) {
    for (int j = kk >> 1; j > 0; j >>= 1) {
      __syncthreads();
      for (int i = threadIdx.x; i < FCAP; i += blockDim.x) {
        int l = i ^ j;
        if (l > i) {
          float vi = sv[i], vl = sv[l];
          int ii = si[i], il = si[l];
          bool before = (vi > vl) || (vi == vl && ii < il);
          bool up = ((i & kk) == 0);
          if (up != before) { sv[i] = vl; sv[l] = vi; si[i] = il; si[l] = ii; }
        }
      }
    }
  }
  __syncthreads();

  if ((int)threadIdx.x < topk) {
    int o = threadIdx.x;
    float v = sv[o];
    int idx = si[o];
    bool valid = (idx != 0x7FFFFFFF) && (v > THRESH);
    int safe = valid ? idx : 0;
    int pair = safe / Kc;
    int act = safe - pair * Kc;
    float4 pb = pbox[pair];
    float4 ob = obox[pair];
    // output layout (all fp32): scores[100] | pboxes[400] | oboxes[400] |
    //                           oclass[100] | action[100] | valid[100]
    out[o] = valid ? v : 0.0f;
    float* pdst = out + topk + 4 * o;
    pdst[0] = pb.x; pdst[1] = pb.y; pdst[2] = pb.z; pdst[3] = pb.w;
    float* odst = out + 5 * topk + 4 * o;
    odst[0] = ob.x; odst[1] = ob.y; odst[2] = ob.z; odst[3] = ob.w;
    out[9 * topk + o] = (float)ocls[pair];
    out[10 * topk + o] = (float)act;
    out[11 * topk + o] = valid ? 1.0f : 0.0f;
  }
}

extern "C" void kernel_launch(void* const* d_in, const int* in_sizes, int n_in,
                              void* d_out, int out_size, void* d_ws, size_t ws_size,
                              hipStream_t stream) {
  const float* pbox = (const float*)d_in[0];   // (R,4)
  const float* obox = (const float*)d_in[1];   // (R,4)
  const float* ps   = (const float*)d_in[2];   // (R,)
  const float* os   = (const float*)d_in[3];   // (R,)
  const int*   ocls = (const int*)d_in[4];     // (R,1) int32
  const float* hoi  = (const float*)d_in[5];   // (R,K)
  float* out = (float*)d_out;

  const int R    = in_sizes[2];
  const int N    = in_sizes[5];
  const int Kc   = N / R;                      // 117
  const int topk = out_size / 12;              // 100+400+400+100+100+100

  // workspace layout: [0]=cand_cnt, [1..2]=meta(T,mode), [8..583]=hist,
  // byte 4096: cand_v[CAP], then cand_i[CAP]   (total < 72 KiB)
  int* g_cnt  = (int*)d_ws;
  int* g_meta = g_cnt + 1;
  int* g_hist = g_cnt + 8;
  float* cand_v = (float*)((char*)d_ws + 4096);
  int*   cand_i = (int*)((char*)d_ws + 4096 + CAP * sizeof(float));

  hipMemsetAsync(d_ws, 0, 4096, stream);       // zero cnt+meta+hist

  const int N4 = N / 4;
  dim3 grid(512), block(512);
  if (Kc == 117) {
    k_hist<117><<<grid, block, 0, stream>>>((const float4*)hoi, ps, os, N4, N,
                                            Kc, g_hist, g_cnt, cand_v, cand_i);
  } else {
    k_hist<0><<<grid, block, 0, stream>>>((const float4*)hoi, ps, os, N4, N,
                                          Kc, g_hist, g_cnt, cand_v, cand_i);
  }
  k_thresh<<<1, NB, 0, stream>>>(g_hist, g_cnt, g_meta, topk);
  if (Kc == 117) {
    k_collect<117><<<grid, block, 0, stream>>>((const float4*)hoi, ps, os, N4,
                                               N, Kc, g_meta, g_cnt, cand_v,
                                               cand_i);
  } else {
    k_collect<0><<<grid, block, 0, stream>>>((const float4*)hoi, ps, os, N4, N,
                                             Kc, g_meta, g_cnt, cand_v, cand_i);
  }
  k_final<<<1, 1024, 0, stream>>>(cand_v, cand_i, g_cnt, g_meta,
                                  (const float4*)pbox, (const float4*)obox,
                                  ocls, out, topk, Kc);
}

// Round 2
// 243.557 us; speedup vs baseline: 1.0794x; 1.0794x over previous
//
#include <hip/hip_runtime.h>

// ---------------------------------------------------------------------------
// HOI top-k, R=262144 x K=117, topk=100, thresh=0.05
//
//  K1 k_hist     : full pass (4 independent float4 loads/iter, 32 waves/CU).
//                  Histograms ONLY values > 0.75 (76-bin window) and collects
//                  candidates >= ~0.898 (bin G_REL) into a global buffer.
//  K2 k_thresh   : 1 block; exact cutoff bin T from window hist; fast iff
//                  T >= G_REL and no buffer overflow.
//  K3 k_fallback : 1 block; normally exits immediately. Otherwise: full
//                  576-bin histogram + exact T + re-collect (slow but exact).
//  K4 k_final    : 1 block; filter cands to bins >= T, dynamic-size bitonic
//                  sort (value desc, index asc = stable top_k ties), write.
// ---------------------------------------------------------------------------

#define NB        576          // full histogram bins (top-16 float bits - base)
#define BIN_BASE  15692        // (bits of 0.05f) >> 16
#define WLO       500          // window start: bin of 0.75f (0x3F40)
#define WN        80           // window bins (576-500=76, padded)
#define VLO       0.75f        // value at bin WLO
#define G_REL     538          // bin of 0.8984375 -> opportunistic collect
#define CAP       8192         // global candidate capacity
#define FCAP      2048         // K4 max sort size (power of 2)
#define THRESH    0.05f
#define NEG_INF   __int_as_float(0xFF800000)

__device__ __forceinline__ int bin_of(float s) {
  // valid only for s > 0 (positive floats: bit order == value order)
  int b = (int)(__float_as_uint(s) >> 16) - BIN_BASE;
  return b > (NB - 1) ? (NB - 1) : b;
}

template <int KC>
__global__ __launch_bounds__(256) void k_hist(
    const float4* __restrict__ hoi4, const float* __restrict__ ps,
    const float* __restrict__ os, int N4, int N, int Kc,
    int* __restrict__ g_whist, int* __restrict__ g_cnt,
    float* __restrict__ cand_v, int* __restrict__ cand_i) {
  __shared__ int lh[WN];
  if (threadIdx.x < WN) lh[threadIdx.x] = 0;
  __syncthreads();

  const int k = KC ? KC : Kc;
  const int TT = gridDim.x * blockDim.x;
  const int tid = blockIdx.x * blockDim.x + threadIdx.x;

  auto process = [&](int t, float4 h) {
    int i0 = 4 * t;
    int q = i0 / k;                       // constant k -> magic mul
    int rem = i0 - q * k;
    float bsa = ps[q] * os[q];            // box_scores = p*o (matches ref)
    int qb = (rem + 3 >= k) ? q + 1 : q;  // row crossing within the float4
    float bsb = ps[qb] * os[qb];
    float vals[4] = {h.x, h.y, h.z, h.w};
#pragma unroll
    for (int j = 0; j < 4; ++j) {
      float bs = (rem + j >= k) ? bsb : bsa;
      float s = vals[j] * bs;             // scores = hoi * box_scores
      if (s > VLO) {
        int b = bin_of(s);
        atomicAdd(&lh[b - WLO], 1);
        if (b >= G_REL) {
          int slot = atomicAdd(g_cnt, 1);
          if (slot < CAP) { cand_v[slot] = s; cand_i[slot] = i0 + j; }
        }
      }
    }
  };

  for (int t0 = tid; t0 < N4; t0 += 4 * TT) {
    int t1 = t0 + TT, t2 = t0 + 2 * TT, t3 = t0 + 3 * TT;
    // 4 independent loads in flight per iteration (MLP)
    float4 h0 = hoi4[t0];
    float4 h1 = hoi4[t1 < N4 ? t1 : t0];
    float4 h2 = hoi4[t2 < N4 ? t2 : t0];
    float4 h3 = hoi4[t3 < N4 ? t3 : t0];
    process(t0, h0);
    if (t1 < N4) process(t1, h1);
    if (t2 < N4) process(t2, h2);
    if (t3 < N4) process(t3, h3);
  }
  // scalar tail (N % 4) — block 0 only
  if (blockIdx.x == 0) {
    const float* hoi = (const float*)hoi4;
    for (int i = N4 * 4 + threadIdx.x; i < N; i += blockDim.x) {
      int q = i / k;
      float s = hoi[i] * (ps[q] * os[q]);
      if (s > VLO) {
        int b = bin_of(s);
        atomicAdd(&lh[b - WLO], 1);
        if (b >= G_REL) {
          int slot = atomicAdd(g_cnt, 1);
          if (slot < CAP) { cand_v[slot] = s; cand_i[slot] = i; }
        }
      }
    }
  }
  __syncthreads();
  if (threadIdx.x < WN) {
    int c = lh[threadIdx.x];
    if (c) atomicAdd(&g_whist[threadIdx.x], c);
  }
}

__global__ void k_thresh(const int* __restrict__ g_whist,
                         int* __restrict__ g_cnt, int* __restrict__ g_meta,
                         int topk) {
  __shared__ int wh[WN];
  if (threadIdx.x < WN) wh[threadIdx.x] = g_whist[threadIdx.x];
  __syncthreads();
  if (threadIdx.x == 0) {
    int cum = 0, T = -1;
#pragma unroll
    for (int b = WN - 1; b >= 0; --b) {  // break-free -> pipelined LDS reads
      cum += wh[b];
      if (T < 0 && cum >= topk) T = b + WLO;
    }
    int cnt = g_cnt[0];
    int fast = (T >= G_REL && cnt <= CAP) ? 1 : 0;
    g_meta[0] = T;
    g_meta[1] = fast ? 0 : 1;
    if (!fast) g_cnt[0] = 0;  // fallback recollects from scratch
  }
}

// Slow-but-exact path; normally exits immediately (meta[1]==0).
__global__ __launch_bounds__(1024) void k_fallback(
    const float* __restrict__ hoi, const float* __restrict__ ps,
    const float* __restrict__ os, int N, int Kc,
    int* __restrict__ g_meta, int* __restrict__ g_cnt,
    float* __restrict__ cand_v, int* __restrict__ cand_i, int topk) {
  if (g_meta[1] == 0) return;
  __shared__ int lh[NB];
  __shared__ int sT;
  for (int b = threadIdx.x; b < NB; b += blockDim.x) lh[b] = 0;
  __syncthreads();
  for (int i = threadIdx.x; i < N; i += blockDim.x) {
    int q = i / Kc;
    float s = hoi[i] * (ps[q] * os[q]);
    if (s > THRESH) atomicAdd(&lh[bin_of(s)], 1);
  }
  __syncthreads();
  if (threadIdx.x == 0) {
    int cum = 0, T = 0;
    for (int b = NB - 1; b >= 0; --b) {
      cum += lh[b];
      if (cum >= topk) { T = b; break; }
    }
    g_meta[0] = T;
    sT = T;
  }
  __syncthreads();
  const int T = sT;
  for (int i = threadIdx.x; i < N; i += blockDim.x) {
    int q = i / Kc;
    float s = hoi[i] * (ps[q] * os[q]);
    if (s > THRESH && bin_of(s) >= T) {
      int slot = atomicAdd(g_cnt, 1);
      if (slot < CAP) { cand_v[slot] = s; cand_i[slot] = i; }
    }
  }
}

__global__ __launch_bounds__(1024) void k_final(
    const float* __restrict__ cand_v, const int* __restrict__ cand_i,
    const int* __restrict__ g_cnt, const int* __restrict__ g_meta,
    const float4* __restrict__ pbox, const float4* __restrict__ obox,
    const int* __restrict__ ocls, float* __restrict__ out, int topk, int Kc) {
  __shared__ float sv[FCAP];
  __shared__ int si[FCAP];
  __shared__ int scnt;
  if (threadIdx.x == 0) scnt = 0;
  __syncthreads();

  const int T = g_meta[0];
  int n = g_cnt[0];
  if (n > CAP) n = CAP;
  for (int t = threadIdx.x; t < n; t += blockDim.x) {
    float v = cand_v[t];
    if (bin_of(v) >= T) {
      int slot = atomicAdd(&scnt, 1);
      if (slot < FCAP) { sv[slot] = v; si[slot] = cand_i[t]; }
    }
  }
  __syncthreads();
  int m = scnt > FCAP ? FCAP : scnt;
  int P = 128;                 // >= topk; dynamic power-of-2 sort size
  while (P < m) P <<= 1;
  for (int t = threadIdx.x + m; t < P; t += blockDim.x) {
    sv[t] = NEG_INF;
    si[t] = 0x7FFFFFFF;
  }

  // bitonic sort [0,P): value desc, index asc (stable-top_k tie order)
  for (int kk = 2; kk <= P; kk <<= 1) {
    for (int j = kk >> 1; j > 0; j >>= 1) {
      __syncthreads();
      for (int i = threadIdx.x; i < P; i += blockDim.x) {
        int l = i ^ j;
        if (l > i) {
          float vi = sv[i], vl = sv[l];
          int ii = si[i], il = si[l];
          bool before = (vi > vl) || (vi == vl && ii < il);
          bool up = ((i & kk) == 0);
          if (up != before) { sv[i] = vl; sv[l] = vi; si[i] = il; si[l] = ii; }
        }
      }
    }
  }
  __syncthreads();

  if ((int)threadIdx.x < topk) {
    int o = threadIdx.x;
    float v = sv[o];
    int idx = si[o];
    bool valid = (idx != 0x7FFFFFFF) && (v > THRESH);
    int safe = valid ? idx : 0;
    int pair = safe / Kc;
    int act = safe - pair * Kc;
    float4 pb = pbox[pair];
    float4 ob = obox[pair];
    // output: scores[100] | pboxes[400] | oboxes[400] | ocls[100] |
    //         action[100] | valid[100]   (all fp32)
    out[o] = valid ? v : 0.0f;
    float* pdst = out + topk + 4 * o;
    pdst[0] = pb.x; pdst[1] = pb.y; pdst[2] = pb.z; pdst[3] = pb.w;
    float* odst = out + 5 * topk + 4 * o;
    odst[0] = ob.x; odst[1] = ob.y; odst[2] = ob.z; odst[3] = ob.w;
    out[9 * topk + o] = (float)ocls[pair];
    out[10 * topk + o] = (float)act;
    out[11 * topk + o] = valid ? 1.0f : 0.0f;
  }
}

extern "C" void kernel_launch(void* const* d_in, const int* in_sizes, int n_in,
                              void* d_out, int out_size, void* d_ws, size_t ws_size,
                              hipStream_t stream) {
  const float* pbox = (const float*)d_in[0];
  const float* obox = (const float*)d_in[1];
  const float* ps   = (const float*)d_in[2];
  const float* os   = (const float*)d_in[3];
  const int*   ocls = (const int*)d_in[4];
  const float* hoi  = (const float*)d_in[5];
  float* out = (float*)d_out;

  const int R    = in_sizes[2];
  const int N    = in_sizes[5];
  const int Kc   = N / R;              // 117
  const int topk = out_size / 12;      // 100

  // ws: [0]=cand_cnt, [1..2]=meta(T,mode), [8..87]=window hist;
  // byte 4096: cand_v[CAP]; then cand_i[CAP]
  int* g_cnt   = (int*)d_ws;
  int* g_meta  = g_cnt + 1;
  int* g_whist = g_cnt + 8;
  float* cand_v = (float*)((char*)d_ws + 4096);
  int*   cand_i = (int*)((char*)d_ws + 4096 + CAP * sizeof(float));

  hipMemsetAsync(d_ws, 0, 4096, stream);

  const int N4 = N / 4;
  if (Kc == 117) {
    k_hist<117><<<2048, 256, 0, stream>>>((const float4*)hoi, ps, os, N4, N,
                                          Kc, g_whist, g_cnt, cand_v, cand_i);
  } else {
    k_hist<0><<<2048, 256, 0, stream>>>((const float4*)hoi, ps, os, N4, N, Kc,
                                        g_whist, g_cnt, cand_v, cand_i);
  }
  k_thresh<<<1, 128, 0, stream>>>(g_whist, g_cnt, g_meta, topk);
  k_fallback<<<1, 1024, 0, stream>>>(hoi, ps, os, N, Kc, g_meta, g_cnt,
                                     cand_v, cand_i, topk);
  k_final<<<1, 1024, 0, stream>>>(cand_v, cand_i, g_cnt, g_meta,
                                  (const float4*)pbox, (const float4*)obox,
                                  ocls, out, topk, Kc);
}